// Round 4
// baseline (677.124 us; speedup 1.0000x reference)
//
#include <hip/hip_runtime.h>
#include <stdint.h>

// ---------------------------------------------------------------------------
// GCN 2-layer: out = Ahat( dropout(elu( Ahat(x@W1)+b1 )) @ W2 ) + b2
// Ahat = D^-1/2 (A+I) D^-1/2
// dropout = jax threefry2x32 key(42), p=0.25, partitionable path:
//   bits[j] = o0^o1 of threefry(key,(0,j)); u = bitcast((bits>>9)|1.0f)-1
// R3->R4: GEMM1 = split-bf16 MFMA (hi*hi+hi*lo+lo*hi), LDS-free, direct
// global fragment loads; gather1 fused with elu/dropout/W2-dot epilogue.
// ---------------------------------------------------------------------------

typedef __bf16 bf16x8 __attribute__((ext_vector_type(8)));
typedef float floatx4 __attribute__((ext_vector_type(4)));

union BF8 {
  bf16x8 v;
  unsigned short u[8];
  uint4 q;
};

// ---------------- Threefry-2x32, key = (0, 42), 20 rounds ------------------
__device__ __forceinline__ void tf_round(uint32_t& x0, uint32_t& x1, int r) {
  x0 += x1;
  x1 = (x1 << r) | (x1 >> (32 - r));
  x1 ^= x0;
}

__device__ __forceinline__ void threefry_0_42(uint32_t c0, uint32_t c1,
                                              uint32_t& o0, uint32_t& o1) {
  const uint32_t ks0 = 0u;
  const uint32_t ks1 = 42u;
  const uint32_t ks2 = 0x1BD11BDAu ^ 0u ^ 42u;
  uint32_t x0 = c0 + ks0;
  uint32_t x1 = c1 + ks1;
  tf_round(x0, x1, 13); tf_round(x0, x1, 15); tf_round(x0, x1, 26); tf_round(x0, x1, 6);
  x0 += ks1; x1 += ks2 + 1u;
  tf_round(x0, x1, 17); tf_round(x0, x1, 29); tf_round(x0, x1, 16); tf_round(x0, x1, 24);
  x0 += ks2; x1 += ks0 + 2u;
  tf_round(x0, x1, 13); tf_round(x0, x1, 15); tf_round(x0, x1, 26); tf_round(x0, x1, 6);
  x0 += ks0; x1 += ks1 + 3u;
  tf_round(x0, x1, 17); tf_round(x0, x1, 29); tf_round(x0, x1, 16); tf_round(x0, x1, 24);
  x0 += ks1; x1 += ks2 + 4u;
  tf_round(x0, x1, 13); tf_round(x0, x1, 15); tf_round(x0, x1, 26); tf_round(x0, x1, 6);
  x0 += ks2; x1 += ks0 + 5u;
  o0 = x0; o1 = x1;
}

// split fp32 -> bf16 hi (truncate) + bf16 lo (truncate of residual)
__device__ __forceinline__ void split_bf16(float x, unsigned short& hi, unsigned short& lo) {
  uint32_t b = __float_as_uint(x);
  hi = (unsigned short)(b >> 16);
  float hif = __uint_as_float(b & 0xffff0000u);
  float lof = x - hif;  // exact
  lo = (unsigned short)(__float_as_uint(lof) >> 16);
}

// ---------------- degree / dinv --------------------------------------------
__global__ void k_deg(const int* __restrict__ dst, int E, int* __restrict__ deg) {
  int e = blockIdx.x * blockDim.x + threadIdx.x;
  if (e < E) atomicAdd(&deg[dst[e]], 1);
}

__global__ void k_dinv(const int* __restrict__ deg, float* __restrict__ dinv, int N) {
  int n = blockIdx.x * blockDim.x + threadIdx.x;
  if (n < N) {
    float d = (float)(deg[n] + 1);  // +1 self loop
    dinv[n] = 1.0f / sqrtf(d);
  }
}

// ---------------- exclusive scan (single block, 1024 thr) ------------------
__global__ __launch_bounds__(1024) void k_scan(const int* __restrict__ deg,
                                               int* __restrict__ rowptr, int N) {
  __shared__ int smem[1024];
  __shared__ int base_s;
  int tid = threadIdx.x;
  if (tid == 0) base_s = 0;
  __syncthreads();
  for (int start = 0; start < N; start += 1024) {
    int i = start + tid;
    int v = (i < N) ? deg[i] : 0;
    smem[tid] = v;
    __syncthreads();
#pragma unroll
    for (int off = 1; off < 1024; off <<= 1) {
      int t = (tid >= off) ? smem[tid - off] : 0;
      __syncthreads();
      smem[tid] += t;
      __syncthreads();
    }
    int incl = smem[tid];
    int base = base_s;
    if (i < N) rowptr[i] = base + incl - v;  // exclusive
    __syncthreads();
    if (tid == 1023) base_s = base + incl;
    __syncthreads();
  }
  if (tid == 0) rowptr[N] = base_s;
}

// ---------------- bucket edges by dst --------------------------------------
__global__ void k_bucket(const int* __restrict__ src, const int* __restrict__ dst,
                         int* __restrict__ cursor, int* __restrict__ csr_src, int E) {
  int e = blockIdx.x * blockDim.x + threadIdx.x;
  if (e < E) {
    int pos = atomicAdd(&cursor[dst[e]], 1);
    csr_src[pos] = src[e];
  }
}

// -------- prep: W1 [512][256] fp32 -> W1T hi/lo [256][512] bf16 ------------
__global__ void k_prep_w1t(const float* __restrict__ W1,
                           unsigned short* __restrict__ w1t_hi,
                           unsigned short* __restrict__ w1t_lo) {
  int t = blockIdx.x * blockDim.x + threadIdx.x;  // t = k*256+n
  if (t >= 512 * 256) return;
  int k = t >> 8, n = t & 255;
  unsigned short hi, lo;
  split_bf16(W1[t], hi, lo);
  w1t_hi[n * 512 + k] = hi;
  w1t_lo[n * 512 + k] = lo;
}

// -------- GEMM1 via split-bf16 MFMA: h = x @ W1  ---------------------------
// block = 256 thr (4 waves); wave w computes rows [blk*64 + w*16, +16) x 256.
// A frags direct from global x (row-major = A-operand layout).
// B frags direct from global W1T hi/lo (L2-resident, [n][k] layout).
__global__ __launch_bounds__(256) void k_gemm_mfma(
    const float* __restrict__ A,            // [M,512]
    const unsigned short* __restrict__ bhi, // [256][512]
    const unsigned short* __restrict__ blo, // [256][512]
    float* __restrict__ C,                  // [M,256]
    int M) {
  const int K = 512;
  const int wave = threadIdx.x >> 6;
  const int lane = threadIdx.x & 63;
  const int quad = lane >> 4;
  const int l16 = lane & 15;

  const int m0 = blockIdx.x * 64 + wave * 16;  // wave's 16 rows
  const int grow = m0 + l16;                   // this lane's A row
  const bool rowok = grow < M;

  floatx4 acc[16];
#pragma unroll
  for (int i = 0; i < 16; ++i) acc[i] = (floatx4){0.f, 0.f, 0.f, 0.f};

  const float* arow = A + (size_t)(rowok ? grow : 0) * K;

  for (int k0 = 0; k0 < K; k0 += 32) {
    // ---- A fragment: 8 fp32 at [grow][k0 + quad*8 ..] -> hi/lo bf16x8 ----
    float4 a0 = make_float4(0.f, 0.f, 0.f, 0.f), a1 = a0;
    if (rowok) {
      const float* p = arow + k0 + quad * 8;
      a0 = *(const float4*)(p);
      a1 = *(const float4*)(p + 4);
    }
    BF8 ahi, alo;
    {
      float av[8] = {a0.x, a0.y, a0.z, a0.w, a1.x, a1.y, a1.z, a1.w};
#pragma unroll
      for (int j = 0; j < 8; ++j) split_bf16(av[j], ahi.u[j], alo.u[j]);
    }

    const size_t boff = (size_t)l16 * 512 + k0 + quad * 8;
#pragma unroll
    for (int nt = 0; nt < 16; ++nt) {
      BF8 wh, wl;
      wh.q = *(const uint4*)(bhi + (size_t)nt * 16 * 512 + boff);
      wl.q = *(const uint4*)(blo + (size_t)nt * 16 * 512 + boff);
      acc[nt] = __builtin_amdgcn_mfma_f32_16x16x32_bf16(ahi.v, wh.v, acc[nt], 0, 0, 0);
      acc[nt] = __builtin_amdgcn_mfma_f32_16x16x32_bf16(ahi.v, wl.v, acc[nt], 0, 0, 0);
      acc[nt] = __builtin_amdgcn_mfma_f32_16x16x32_bf16(alo.v, wh.v, acc[nt], 0, 0, 0);
    }
  }

  // ---- store: C/D layout col=lane&15, row=quad*4+reg ----
#pragma unroll
  for (int nt = 0; nt < 16; ++nt) {
#pragma unroll
    for (int r = 0; r < 4; ++r) {
      int gm = m0 + quad * 4 + r;
      if (gm < M) C[(size_t)gm * 256 + nt * 16 + l16] = acc[nt][r];
    }
  }
}

// ------- fused gather1 + (+b1 -> elu -> dropout -> dot W2) -----------------
// one wave per dst node, lane covers 4 features (256 = 64*4)
__global__ __launch_bounds__(256) void k_gather_fused(
    const int* __restrict__ rowptr, const int* __restrict__ csr_src,
    const float* __restrict__ dinv, const float* __restrict__ h,
    const float* __restrict__ b1, const float* __restrict__ W2,
    float* __restrict__ z, int N) {
  int wave = (blockIdx.x * blockDim.x + threadIdx.x) >> 6;
  int lane = threadIdx.x & 63;
  if (wave >= N) return;
  int d = wave;
  float dd = dinv[d];
  int beg = rowptr[d], end = rowptr[d + 1];
  int f0 = lane << 2;

  float4 v = *(const float4*)(h + ((size_t)d << 8) + f0);
  float sw = dd * dd;
  float4 agg = make_float4(v.x * sw, v.y * sw, v.z * sw, v.w * sw);

  for (int e = beg; e < end; ++e) {
    int s = csr_src[e];
    float norm = dinv[s] * dd;
    float4 hv = *(const float4*)(h + ((size_t)s << 8) + f0);
    agg.x += norm * hv.x;
    agg.y += norm * hv.y;
    agg.z += norm * hv.z;
    agg.w += norm * hv.w;
  }

  // epilogue: bias, elu, threefry dropout, dot W2
  float4 bb = *(const float4*)(b1 + f0);
  float4 w  = *(const float4*)(W2 + f0);
  float acc = 0.f;
  uint32_t jbase = ((uint32_t)d << 8) + (uint32_t)f0;
#pragma unroll
  for (int i = 0; i < 4; ++i) {
    uint32_t r0, r1;
    threefry_0_42(0u, jbase + i, r0, r1);  // ctr = (hi=0, lo=j)
    uint32_t bits = r0 ^ r1;
    float u = __uint_as_float((bits >> 9) | 0x3f800000u) - 1.0f;
    float va = (&agg.x)[i] + (&bb.x)[i];
    float ea = va > 0.f ? va : expm1f(va);
    float ha = (u < 0.75f) ? (ea * (1.0f / 0.75f)) : 0.f;
    acc += ha * (&w.x)[i];
  }
#pragma unroll
  for (int off = 32; off > 0; off >>= 1) acc += __shfl_down(acc, off, 64);
  if (lane == 0) z[d] = acc;
}

// ------- gather layer 2 (scalar feature): one wave per node ----------------
__global__ __launch_bounds__(256) void k_gather2(
    const int* __restrict__ rowptr, const int* __restrict__ csr_src,
    const float* __restrict__ dinv, const float* __restrict__ z,
    const float* __restrict__ b2, float* __restrict__ out, int N) {
  int wave = (blockIdx.x * blockDim.x + threadIdx.x) >> 6;
  int lane = threadIdx.x & 63;
  if (wave >= N) return;
  int d = wave;
  float dd = dinv[d];
  int beg = rowptr[d], end = rowptr[d + 1];

  float acc = 0.f;
  for (int e = beg + lane; e < end; e += 64) {
    int s = csr_src[e];
    acc += dinv[s] * z[s];
  }
#pragma unroll
  for (int off = 32; off > 0; off >>= 1) acc += __shfl_down(acc, off, 64);
  if (lane == 0) out[d] = b2[0] + dd * dd * z[d] + dd * acc;
}

// ---------------------------------------------------------------------------
extern "C" void kernel_launch(void* const* d_in, const int* in_sizes, int n_in,
                              void* d_out, int out_size, void* d_ws, size_t ws_size,
                              hipStream_t stream) {
  const float* x  = (const float*)d_in[0];
  const int*   ei = (const int*)d_in[1];   // [2,E] int32
  const float* W1 = (const float*)d_in[2];
  const float* b1 = (const float*)d_in[3];
  const float* W2 = (const float*)d_in[4];
  const float* b2 = (const float*)d_in[5];
  float* out = (float*)d_out;

  const int E = in_sizes[1] / 2;
  const int N = in_sizes[0] / 512;  // 50000
  const int* src = ei;
  const int* dst = ei + E;

  char* ws = (char*)d_ws;
  size_t off = 0;
  auto alloc = [&](size_t bytes) -> void* {
    void* p = ws + off;
    off += (bytes + 255) & ~(size_t)255;
    return p;
  };
  int*   deg     = (int*)  alloc((size_t)N * 4);
  int*   rowptr  = (int*)  alloc((size_t)(N + 1) * 4);
  int*   cursor  = (int*)  alloc((size_t)N * 4);
  int*   csr_src = (int*)  alloc((size_t)E * 4);          // 3.2 MB
  float* dinv    = (float*)alloc((size_t)N * 4);
  float* h       = (float*)alloc((size_t)N * 256 * 4);    // 51.2 MB
  float* z       = (float*)alloc((size_t)N * 4);
  unsigned short* w1t_hi = (unsigned short*)alloc(256 * 512 * 2);  // 256 KB
  unsigned short* w1t_lo = (unsigned short*)alloc(256 * 512 * 2);

  hipMemsetAsync(deg, 0, (size_t)N * 4, stream);
  k_prep_w1t<<<(512 * 256 + 255) / 256, 256, 0, stream>>>(W1, w1t_hi, w1t_lo);
  k_deg<<<(E + 255) / 256, 256, 0, stream>>>(dst, E, deg);
  k_dinv<<<(N + 255) / 256, 256, 0, stream>>>(deg, dinv, N);
  k_scan<<<1, 1024, 0, stream>>>(deg, rowptr, N);
  hipMemcpyAsync(cursor, rowptr, (size_t)N * 4, hipMemcpyDeviceToDevice, stream);
  k_bucket<<<(E + 255) / 256, 256, 0, stream>>>(src, dst, cursor, csr_src, E);

  k_gemm_mfma<<<(N + 63) / 64, 256, 0, stream>>>(x, w1t_hi, w1t_lo, h, N);

  k_gather_fused<<<(N * 64 + 255) / 256, 256, 0, stream>>>(rowptr, csr_src, dinv, h,
                                                           b1, W2, z, N);
  k_gather2<<<(N * 64 + 255) / 256, 256, 0, stream>>>(rowptr, csr_src, dinv, z, b2, out, N);
}

// Round 5
// 526.290 us; speedup vs baseline: 1.2866x; 1.2866x over previous
//
#include <hip/hip_runtime.h>
#include <stdint.h>

// ---------------------------------------------------------------------------
// GCN 2-layer: out = Ahat( dropout(elu( Ahat(x@W1)+b1 )) @ W2 ) + b2
// Ahat = D^-1/2 (A+I) D^-1/2
// dropout = jax threefry2x32 key(42), p=0.25, partitionable path.
// R4->R5: B packed fragment-major (coalesced loads), 32 rows/wave (B reuse),
//         h stored fp16 (halves gather traffic), parallel 3-phase scan.
// ---------------------------------------------------------------------------

typedef __bf16 bf16x8 __attribute__((ext_vector_type(8)));
typedef float floatx4 __attribute__((ext_vector_type(4)));
typedef _Float16 f16;
typedef _Float16 f16x4 __attribute__((ext_vector_type(4)));

union BF8 {
  bf16x8 v;
  unsigned short u[8];
  uint4 q;
};

// ---------------- Threefry-2x32, key = (0, 42), 20 rounds ------------------
__device__ __forceinline__ void tf_round(uint32_t& x0, uint32_t& x1, int r) {
  x0 += x1;
  x1 = (x1 << r) | (x1 >> (32 - r));
  x1 ^= x0;
}

__device__ __forceinline__ void threefry_0_42(uint32_t c0, uint32_t c1,
                                              uint32_t& o0, uint32_t& o1) {
  const uint32_t ks0 = 0u;
  const uint32_t ks1 = 42u;
  const uint32_t ks2 = 0x1BD11BDAu ^ 0u ^ 42u;
  uint32_t x0 = c0 + ks0;
  uint32_t x1 = c1 + ks1;
  tf_round(x0, x1, 13); tf_round(x0, x1, 15); tf_round(x0, x1, 26); tf_round(x0, x1, 6);
  x0 += ks1; x1 += ks2 + 1u;
  tf_round(x0, x1, 17); tf_round(x0, x1, 29); tf_round(x0, x1, 16); tf_round(x0, x1, 24);
  x0 += ks2; x1 += ks0 + 2u;
  tf_round(x0, x1, 13); tf_round(x0, x1, 15); tf_round(x0, x1, 26); tf_round(x0, x1, 6);
  x0 += ks0; x1 += ks1 + 3u;
  tf_round(x0, x1, 17); tf_round(x0, x1, 29); tf_round(x0, x1, 16); tf_round(x0, x1, 24);
  x0 += ks1; x1 += ks2 + 4u;
  tf_round(x0, x1, 13); tf_round(x0, x1, 15); tf_round(x0, x1, 26); tf_round(x0, x1, 6);
  x0 += ks2; x1 += ks0 + 5u;
  o0 = x0; o1 = x1;
}

// split fp32 -> bf16 hi (truncate) + bf16 lo (truncate of residual)
__device__ __forceinline__ void split_bf16(float x, unsigned short& hi, unsigned short& lo) {
  uint32_t b = __float_as_uint(x);
  hi = (unsigned short)(b >> 16);
  float hif = __uint_as_float(b & 0xffff0000u);
  float lof = x - hif;  // exact
  lo = (unsigned short)(__float_as_uint(lof) >> 16);
}

__device__ __forceinline__ float4 ld4h(const f16* p) {
  f16x4 v = *(const f16x4*)p;
  return make_float4((float)v.x, (float)v.y, (float)v.z, (float)v.w);
}

// ---------------- degree / dinv --------------------------------------------
__global__ void k_deg(const int* __restrict__ dst, int E, int* __restrict__ deg) {
  int e = blockIdx.x * blockDim.x + threadIdx.x;
  if (e < E) atomicAdd(&deg[dst[e]], 1);
}

__global__ void k_dinv(const int* __restrict__ deg, float* __restrict__ dinv, int N) {
  int n = blockIdx.x * blockDim.x + threadIdx.x;
  if (n < N) {
    float d = (float)(deg[n] + 1);  // +1 self loop
    dinv[n] = 1.0f / sqrtf(d);
  }
}

// ---------------- 3-phase exclusive scan -----------------------------------
__global__ __launch_bounds__(256) void k_scan1(const int* __restrict__ deg,
                                               int* __restrict__ excl,
                                               int* __restrict__ sums, int N) {
  __shared__ int sm[256];
  int tid = threadIdx.x;
  int i = blockIdx.x * 256 + tid;
  int v = (i < N) ? deg[i] : 0;
  sm[tid] = v;
  __syncthreads();
#pragma unroll
  for (int off = 1; off < 256; off <<= 1) {
    int t = (tid >= off) ? sm[tid - off] : 0;
    __syncthreads();
    sm[tid] += t;
    __syncthreads();
  }
  if (i < N) excl[i] = sm[tid] - v;
  if (tid == 255) sums[blockIdx.x] = sm[255];
}

__global__ __launch_bounds__(1024) void k_scan2(int* __restrict__ sums, int nb) {
  __shared__ int sm[1024];
  int tid = threadIdx.x;
  int v = (tid < nb) ? sums[tid] : 0;
  sm[tid] = v;
  __syncthreads();
#pragma unroll
  for (int off = 1; off < 1024; off <<= 1) {
    int t = (tid >= off) ? sm[tid - off] : 0;
    __syncthreads();
    sm[tid] += t;
    __syncthreads();
  }
  if (tid < nb) sums[tid] = sm[tid] - v;  // exclusive, in place
}

__global__ void k_scan3(int* __restrict__ rowptr, const int* __restrict__ sums,
                        int N, int E) {
  int i = blockIdx.x * blockDim.x + threadIdx.x;
  if (i < N) rowptr[i] += sums[i >> 8];
  if (i == 0) rowptr[N] = E;
}

// ---------------- bucket edges by dst --------------------------------------
__global__ void k_bucket(const int* __restrict__ src, const int* __restrict__ dst,
                         int* __restrict__ cursor, int* __restrict__ csr_src, int E) {
  int e = blockIdx.x * blockDim.x + threadIdx.x;
  if (e < E) {
    int pos = atomicAdd(&cursor[dst[e]], 1);
    csr_src[pos] = src[e];
  }
}

// -------- prep: W1 [512][256] fp32 -> packed fragment-major bf16 hi/lo -----
// entry(e) = ((kstep*16 + nt)*2 + plane)*64 + lane, 8 shorts each;
// lane = quad*16 + (n&15), k = kstep*32 + quad*8 + j, nt = n>>4.
__global__ void k_prep_w1t(const float* __restrict__ W1,
                           unsigned short* __restrict__ Bpk) {
  int t = blockIdx.x * blockDim.x + threadIdx.x;  // t = k*256+n
  if (t >= 512 * 256) return;
  int k = t >> 8, n = t & 255;
  unsigned short hi, lo;
  split_bf16(W1[t], hi, lo);
  int ks = k >> 5, quad = (k >> 3) & 3, j = k & 7;
  int nt = n >> 4, lane = quad * 16 + (n & 15);
  size_t ehi = ((size_t)(ks * 16 + nt) * 2) * 64 + lane;
  Bpk[ehi * 8 + j] = hi;
  Bpk[(ehi + 64) * 8 + j] = lo;
}

// -------- GEMM1 via split-bf16 MFMA: h = (f16) x @ W1 ----------------------
// block = 256 thr (4 waves); wave w: rows [blk*128 + w*32, +32) x all 256 cols.
// A frags direct from global x; B frags coalesced from packed (L1/L2-hot).
__global__ __launch_bounds__(256) void k_gemm_mfma(
    const float* __restrict__ A,     // [M,512]
    const uint4* __restrict__ Bpk,   // packed, 32768 uint4
    f16* __restrict__ C,             // [M,256]
    int M) {
  const int K = 512;
  const int wave = threadIdx.x >> 6;
  const int lane = threadIdx.x & 63;
  const int quad = lane >> 4;
  const int l16 = lane & 15;

  const int m0 = blockIdx.x * 128 + wave * 32;
  int r0 = m0 + l16;
  int r1 = m0 + 16 + l16;
  const float* a0p = A + (size_t)(r0 < M ? r0 : M - 1) * K;
  const float* a1p = A + (size_t)(r1 < M ? r1 : M - 1) * K;

  floatx4 acc[2][16];
#pragma unroll
  for (int f = 0; f < 2; ++f)
#pragma unroll
    for (int i = 0; i < 16; ++i) acc[f][i] = (floatx4){0.f, 0.f, 0.f, 0.f};

  for (int ks = 0; ks < 16; ++ks) {
    const int kb = ks * 32 + quad * 8;
    float4 x0 = *(const float4*)(a0p + kb);
    float4 x1 = *(const float4*)(a0p + kb + 4);
    float4 y0 = *(const float4*)(a1p + kb);
    float4 y1 = *(const float4*)(a1p + kb + 4);

    BF8 ahi0, alo0, ahi1, alo1;
    {
      float xv[8] = {x0.x, x0.y, x0.z, x0.w, x1.x, x1.y, x1.z, x1.w};
      float yv[8] = {y0.x, y0.y, y0.z, y0.w, y1.x, y1.y, y1.z, y1.w};
#pragma unroll
      for (int j = 0; j < 8; ++j) {
        split_bf16(xv[j], ahi0.u[j], alo0.u[j]);
        split_bf16(yv[j], ahi1.u[j], alo1.u[j]);
      }
    }

    const uint4* bp = Bpk + (size_t)ks * 2048 + lane;
#pragma unroll
    for (int nt = 0; nt < 16; ++nt) {
      BF8 bh, bl;
      bh.q = bp[nt * 128];
      bl.q = bp[nt * 128 + 64];
      acc[0][nt] = __builtin_amdgcn_mfma_f32_16x16x32_bf16(ahi0.v, bh.v, acc[0][nt], 0, 0, 0);
      acc[0][nt] = __builtin_amdgcn_mfma_f32_16x16x32_bf16(alo0.v, bh.v, acc[0][nt], 0, 0, 0);
      acc[0][nt] = __builtin_amdgcn_mfma_f32_16x16x32_bf16(ahi0.v, bl.v, acc[0][nt], 0, 0, 0);
      acc[1][nt] = __builtin_amdgcn_mfma_f32_16x16x32_bf16(ahi1.v, bh.v, acc[1][nt], 0, 0, 0);
      acc[1][nt] = __builtin_amdgcn_mfma_f32_16x16x32_bf16(alo1.v, bh.v, acc[1][nt], 0, 0, 0);
      acc[1][nt] = __builtin_amdgcn_mfma_f32_16x16x32_bf16(ahi1.v, bl.v, acc[1][nt], 0, 0, 0);
    }
  }

  // store: C/D layout col=lane&15, row=quad*4+reg
#pragma unroll
  for (int f = 0; f < 2; ++f)
#pragma unroll
    for (int nt = 0; nt < 16; ++nt)
#pragma unroll
      for (int r = 0; r < 4; ++r) {
        int gm = m0 + f * 16 + quad * 4 + r;
        if (gm < M) C[(size_t)gm * 256 + nt * 16 + l16] = (f16)acc[f][nt][r];
      }
}

// ------- fused gather1 + (+b1 -> elu -> dropout -> dot W2) -----------------
// one wave per dst node, lane covers 4 features; h is fp16
__global__ __launch_bounds__(256) void k_gather_fused(
    const int* __restrict__ rowptr, const int* __restrict__ csr_src,
    const float* __restrict__ dinv, const f16* __restrict__ h,
    const float* __restrict__ b1, const float* __restrict__ W2,
    float* __restrict__ z, int N) {
  int wave = (blockIdx.x * blockDim.x + threadIdx.x) >> 6;
  int lane = threadIdx.x & 63;
  if (wave >= N) return;
  int d = wave;
  float dd = dinv[d];
  int beg = rowptr[d], end = rowptr[d + 1];
  int f0 = lane << 2;

  float4 v = ld4h(h + ((size_t)d << 8) + f0);
  float sw = dd * dd;
  float4 agg = make_float4(v.x * sw, v.y * sw, v.z * sw, v.w * sw);

  for (int e = beg; e < end; ++e) {
    int s = csr_src[e];
    float norm = dinv[s] * dd;
    float4 hv = ld4h(h + ((size_t)s << 8) + f0);
    agg.x += norm * hv.x;
    agg.y += norm * hv.y;
    agg.z += norm * hv.z;
    agg.w += norm * hv.w;
  }

  float4 bb = *(const float4*)(b1 + f0);
  float4 w  = *(const float4*)(W2 + f0);
  float acc = 0.f;
  uint32_t jbase = ((uint32_t)d << 8) + (uint32_t)f0;
#pragma unroll
  for (int i = 0; i < 4; ++i) {
    uint32_t r0, r1;
    threefry_0_42(0u, jbase + i, r0, r1);  // ctr = (hi=0, lo=j)
    uint32_t bits = r0 ^ r1;
    float u = __uint_as_float((bits >> 9) | 0x3f800000u) - 1.0f;
    float va = (&agg.x)[i] + (&bb.x)[i];
    float ea = va > 0.f ? va : expm1f(va);
    float ha = (u < 0.75f) ? (ea * (1.0f / 0.75f)) : 0.f;
    acc += ha * (&w.x)[i];
  }
#pragma unroll
  for (int off = 32; off > 0; off >>= 1) acc += __shfl_down(acc, off, 64);
  if (lane == 0) z[d] = acc;
}

// ------- gather layer 2 (scalar feature): one wave per node ----------------
__global__ __launch_bounds__(256) void k_gather2(
    const int* __restrict__ rowptr, const int* __restrict__ csr_src,
    const float* __restrict__ dinv, const float* __restrict__ z,
    const float* __restrict__ b2, float* __restrict__ out, int N) {
  int wave = (blockIdx.x * blockDim.x + threadIdx.x) >> 6;
  int lane = threadIdx.x & 63;
  if (wave >= N) return;
  int d = wave;
  float dd = dinv[d];
  int beg = rowptr[d], end = rowptr[d + 1];

  float acc = 0.f;
  for (int e = beg + lane; e < end; e += 64) {
    int s = csr_src[e];
    acc += dinv[s] * z[s];
  }
#pragma unroll
  for (int off = 32; off > 0; off >>= 1) acc += __shfl_down(acc, off, 64);
  if (lane == 0) out[d] = b2[0] + dd * dd * z[d] + dd * acc;
}

// ---------------------------------------------------------------------------
extern "C" void kernel_launch(void* const* d_in, const int* in_sizes, int n_in,
                              void* d_out, int out_size, void* d_ws, size_t ws_size,
                              hipStream_t stream) {
  const float* x  = (const float*)d_in[0];
  const int*   ei = (const int*)d_in[1];   // [2,E] int32
  const float* W1 = (const float*)d_in[2];
  const float* b1 = (const float*)d_in[3];
  const float* W2 = (const float*)d_in[4];
  const float* b2 = (const float*)d_in[5];
  float* out = (float*)d_out;

  const int E = in_sizes[1] / 2;
  const int N = in_sizes[0] / 512;  // 50000
  const int* src = ei;
  const int* dst = ei + E;

  char* ws = (char*)d_ws;
  size_t off = 0;
  auto alloc = [&](size_t bytes) -> void* {
    void* p = ws + off;
    off += (bytes + 255) & ~(size_t)255;
    return p;
  };
  int*   deg     = (int*)  alloc((size_t)N * 4);
  int*   rowptr  = (int*)  alloc((size_t)(N + 1) * 4);
  int*   cursor  = (int*)  alloc((size_t)N * 4);
  int*   csr_src = (int*)  alloc((size_t)E * 4);          // 3.2 MB
  int*   sums    = (int*)  alloc(1024 * 4);
  float* dinv    = (float*)alloc((size_t)N * 4);
  f16*   h       = (f16*)  alloc((size_t)N * 256 * 2);    // 25.6 MB
  float* z       = (float*)alloc((size_t)N * 4);
  uint4* Bpk     = (uint4*)alloc(32768 * 16);             // 512 KB packed W1T

  const int nb = (N + 255) / 256;  // 196 scan blocks

  hipMemsetAsync(deg, 0, (size_t)N * 4, stream);
  k_prep_w1t<<<(512 * 256 + 255) / 256, 256, 0, stream>>>(W1, (unsigned short*)Bpk);
  k_deg<<<(E + 255) / 256, 256, 0, stream>>>(dst, E, deg);
  k_dinv<<<(N + 255) / 256, 256, 0, stream>>>(deg, dinv, N);
  k_scan1<<<nb, 256, 0, stream>>>(deg, rowptr, sums, N);
  k_scan2<<<1, 1024, 0, stream>>>(sums, nb);
  k_scan3<<<(N + 255) / 256, 256, 0, stream>>>(rowptr, sums, N, E);
  hipMemcpyAsync(cursor, rowptr, (size_t)N * 4, hipMemcpyDeviceToDevice, stream);
  k_bucket<<<(E + 255) / 256, 256, 0, stream>>>(src, dst, cursor, csr_src, E);

  k_gemm_mfma<<<(N + 127) / 128, 256, 0, stream>>>(x, Bpk, h, N);

  k_gather_fused<<<(N * 64 + 255) / 256, 256, 0, stream>>>(rowptr, csr_src, dinv, h,
                                                           b1, W2, z, N);
  k_gather2<<<(N * 64 + 255) / 256, 256, 0, stream>>>(rowptr, csr_src, dinv, z, b2, out, N);
}

// Round 6
// 412.022 us; speedup vs baseline: 1.6434x; 1.2773x over previous
//
#include <hip/hip_runtime.h>
#include <stdint.h>

// ---------------------------------------------------------------------------
// GCN 2-layer: out = Ahat( dropout(elu( Ahat(x@W1)+b1 )) @ W2 ) + b2
// Ahat = D^-1/2 (A+I) D^-1/2
// dropout = jax threefry2x32 key(42), p=0.25, partitionable path.
// R5->R6: GEMM re-tiled 32x64 per wave (6250 waves, occupancy fix, R5 was
// 1.5 waves/SIMD latency-bound); gather: 2 nodes/wave, 16B loads, unroll-2.
// ---------------------------------------------------------------------------

typedef __bf16 bf16x8 __attribute__((ext_vector_type(8)));
typedef float floatx4 __attribute__((ext_vector_type(4)));
typedef _Float16 f16;
typedef _Float16 f16x8 __attribute__((ext_vector_type(8)));

union BF8 {
  bf16x8 v;
  unsigned short u[8];
  uint4 q;
};

union F16x8 {
  f16x8 v;
  uint4 q;
};

// ---------------- Threefry-2x32, key = (0, 42), 20 rounds ------------------
__device__ __forceinline__ void tf_round(uint32_t& x0, uint32_t& x1, int r) {
  x0 += x1;
  x1 = (x1 << r) | (x1 >> (32 - r));
  x1 ^= x0;
}

__device__ __forceinline__ void threefry_0_42(uint32_t c0, uint32_t c1,
                                              uint32_t& o0, uint32_t& o1) {
  const uint32_t ks0 = 0u;
  const uint32_t ks1 = 42u;
  const uint32_t ks2 = 0x1BD11BDAu ^ 0u ^ 42u;
  uint32_t x0 = c0 + ks0;
  uint32_t x1 = c1 + ks1;
  tf_round(x0, x1, 13); tf_round(x0, x1, 15); tf_round(x0, x1, 26); tf_round(x0, x1, 6);
  x0 += ks1; x1 += ks2 + 1u;
  tf_round(x0, x1, 17); tf_round(x0, x1, 29); tf_round(x0, x1, 16); tf_round(x0, x1, 24);
  x0 += ks2; x1 += ks0 + 2u;
  tf_round(x0, x1, 13); tf_round(x0, x1, 15); tf_round(x0, x1, 26); tf_round(x0, x1, 6);
  x0 += ks0; x1 += ks1 + 3u;
  tf_round(x0, x1, 17); tf_round(x0, x1, 29); tf_round(x0, x1, 16); tf_round(x0, x1, 24);
  x0 += ks1; x1 += ks2 + 4u;
  tf_round(x0, x1, 13); tf_round(x0, x1, 15); tf_round(x0, x1, 26); tf_round(x0, x1, 6);
  x0 += ks2; x1 += ks0 + 5u;
  o0 = x0; o1 = x1;
}

// split fp32 -> bf16 hi (truncate) + bf16 lo (truncate of residual)
__device__ __forceinline__ void split_bf16(float x, unsigned short& hi, unsigned short& lo) {
  uint32_t b = __float_as_uint(x);
  hi = (unsigned short)(b >> 16);
  float hif = __uint_as_float(b & 0xffff0000u);
  float lof = x - hif;  // exact
  lo = (unsigned short)(__float_as_uint(lof) >> 16);
}

// ---------------- degree / dinv --------------------------------------------
__global__ void k_deg(const int* __restrict__ dst, int E, int* __restrict__ deg) {
  int e = blockIdx.x * blockDim.x + threadIdx.x;
  if (e < E) atomicAdd(&deg[dst[e]], 1);
}

__global__ void k_dinv(const int* __restrict__ deg, float* __restrict__ dinv, int N) {
  int n = blockIdx.x * blockDim.x + threadIdx.x;
  if (n < N) {
    float d = (float)(deg[n] + 1);  // +1 self loop
    dinv[n] = 1.0f / sqrtf(d);
  }
}

// ---------------- 3-phase exclusive scan -----------------------------------
__global__ __launch_bounds__(256) void k_scan1(const int* __restrict__ deg,
                                               int* __restrict__ excl,
                                               int* __restrict__ sums, int N) {
  __shared__ int sm[256];
  int tid = threadIdx.x;
  int i = blockIdx.x * 256 + tid;
  int v = (i < N) ? deg[i] : 0;
  sm[tid] = v;
  __syncthreads();
#pragma unroll
  for (int off = 1; off < 256; off <<= 1) {
    int t = (tid >= off) ? sm[tid - off] : 0;
    __syncthreads();
    sm[tid] += t;
    __syncthreads();
  }
  if (i < N) excl[i] = sm[tid] - v;
  if (tid == 255) sums[blockIdx.x] = sm[255];
}

__global__ __launch_bounds__(1024) void k_scan2(int* __restrict__ sums, int nb) {
  __shared__ int sm[1024];
  int tid = threadIdx.x;
  int v = (tid < nb) ? sums[tid] : 0;
  sm[tid] = v;
  __syncthreads();
#pragma unroll
  for (int off = 1; off < 1024; off <<= 1) {
    int t = (tid >= off) ? sm[tid - off] : 0;
    __syncthreads();
    sm[tid] += t;
    __syncthreads();
  }
  if (tid < nb) sums[tid] = sm[tid] - v;  // exclusive, in place
}

__global__ void k_scan3(int* __restrict__ rowptr, const int* __restrict__ sums,
                        int N, int E) {
  int i = blockIdx.x * blockDim.x + threadIdx.x;
  if (i < N) rowptr[i] += sums[i >> 8];
  if (i == 0) rowptr[N] = E;
}

// ---------------- bucket edges by dst --------------------------------------
__global__ void k_bucket(const int* __restrict__ src, const int* __restrict__ dst,
                         int* __restrict__ cursor, int* __restrict__ csr_src, int E) {
  int e = blockIdx.x * blockDim.x + threadIdx.x;
  if (e < E) {
    int pos = atomicAdd(&cursor[dst[e]], 1);
    csr_src[pos] = src[e];
  }
}

// -------- prep: W1 [512][256] fp32 -> packed fragment-major bf16 hi/lo -----
// uint4 entry index = ((ks*16 + nt)*2 + plane)*64 + lane;
// lane = quad*16 + (n&15), k = ks*32 + quad*8 + j, nt = n>>4.
__global__ void k_prep_w1t(const float* __restrict__ W1,
                           unsigned short* __restrict__ Bpk) {
  int t = blockIdx.x * blockDim.x + threadIdx.x;  // t = k*256+n
  if (t >= 512 * 256) return;
  int k = t >> 8, n = t & 255;
  unsigned short hi, lo;
  split_bf16(W1[t], hi, lo);
  int ks = k >> 5, quad = (k >> 3) & 3, j = k & 7;
  int nt = n >> 4, lane = quad * 16 + (n & 15);
  size_t ehi = ((size_t)(ks * 16 + nt) * 2) * 64 + lane;
  Bpk[ehi * 8 + j] = hi;
  Bpk[(ehi + 64) * 8 + j] = lo;
}

// -------- GEMM1 via split-bf16 MFMA: h = (f16) x @ W1 ----------------------
// wave-tile: 32 rows x 64 cols. Block = 4 waves = 32 rows x 256 cols
// (A rows L1-shared). Grid = ceil(M/32) blocks -> ~6250 waves (occupancy).
__global__ __launch_bounds__(256) void k_gemm_mfma(
    const float* __restrict__ A,     // [M,512]
    const uint4* __restrict__ Bpk,   // packed, 32768 uint4 (512 KB, L2-hot)
    f16* __restrict__ C,             // [M,256]
    int M) {
  const int K = 512;
  const int cg = threadIdx.x >> 6;     // col group: nt = cg*4 .. cg*4+3
  const int lane = threadIdx.x & 63;
  const int quad = lane >> 4;
  const int l16 = lane & 15;

  const int m0 = blockIdx.x * 32;
  int r0 = m0 + l16;
  int r1 = m0 + 16 + l16;
  const float* a0p = A + (size_t)(r0 < M ? r0 : M - 1) * K;
  const float* a1p = A + (size_t)(r1 < M ? r1 : M - 1) * K;

  floatx4 acc[2][4];
#pragma unroll
  for (int f = 0; f < 2; ++f)
#pragma unroll
    for (int t = 0; t < 4; ++t) acc[f][t] = (floatx4){0.f, 0.f, 0.f, 0.f};

  // prefetched A registers
  float4 x0 = *(const float4*)(a0p + quad * 8);
  float4 x1 = *(const float4*)(a0p + quad * 8 + 4);
  float4 y0 = *(const float4*)(a1p + quad * 8);
  float4 y1 = *(const float4*)(a1p + quad * 8 + 4);

  for (int ks = 0; ks < 16; ++ks) {
    BF8 ahi0, alo0, ahi1, alo1;
    {
      float xv[8] = {x0.x, x0.y, x0.z, x0.w, x1.x, x1.y, x1.z, x1.w};
      float yv[8] = {y0.x, y0.y, y0.z, y0.w, y1.x, y1.y, y1.z, y1.w};
#pragma unroll
      for (int j = 0; j < 8; ++j) {
        split_bf16(xv[j], ahi0.u[j], alo0.u[j]);
        split_bf16(yv[j], ahi1.u[j], alo1.u[j]);
      }
    }
    if (ks < 15) {  // prefetch next k-step's A
      const int kb = (ks + 1) * 32 + quad * 8;
      x0 = *(const float4*)(a0p + kb);
      x1 = *(const float4*)(a0p + kb + 4);
      y0 = *(const float4*)(a1p + kb);
      y1 = *(const float4*)(a1p + kb + 4);
    }

    const uint4* bp = Bpk + (size_t)ks * 2048 + lane;
#pragma unroll
    for (int t = 0; t < 4; ++t) {
      const int nt = cg * 4 + t;
      BF8 bh, bl;
      bh.q = bp[nt * 128];
      bl.q = bp[nt * 128 + 64];
      acc[0][t] = __builtin_amdgcn_mfma_f32_16x16x32_bf16(ahi0.v, bh.v, acc[0][t], 0, 0, 0);
      acc[0][t] = __builtin_amdgcn_mfma_f32_16x16x32_bf16(alo0.v, bh.v, acc[0][t], 0, 0, 0);
      acc[0][t] = __builtin_amdgcn_mfma_f32_16x16x32_bf16(ahi0.v, bl.v, acc[0][t], 0, 0, 0);
      acc[1][t] = __builtin_amdgcn_mfma_f32_16x16x32_bf16(ahi1.v, bh.v, acc[1][t], 0, 0, 0);
      acc[1][t] = __builtin_amdgcn_mfma_f32_16x16x32_bf16(alo1.v, bh.v, acc[1][t], 0, 0, 0);
      acc[1][t] = __builtin_amdgcn_mfma_f32_16x16x32_bf16(ahi1.v, bl.v, acc[1][t], 0, 0, 0);
    }
  }

  // store: C/D layout col=lane&15, row=quad*4+reg
#pragma unroll
  for (int f = 0; f < 2; ++f)
#pragma unroll
    for (int t = 0; t < 4; ++t) {
      const int col = (cg * 4 + t) * 16 + l16;
#pragma unroll
      for (int r = 0; r < 4; ++r) {
        int gm = m0 + f * 16 + quad * 4 + r;
        if (gm < M) C[(size_t)gm * 256 + col] = (f16)acc[f][t][r];
      }
    }
}

// ------- fused gather1 + (+b1 -> elu -> dropout -> dot W2) -----------------
// one wave serves TWO nodes (half-wave each); lane covers 8 fp16 feats (16B).
__global__ __launch_bounds__(256) void k_gather_fused(
    const int* __restrict__ rowptr, const int* __restrict__ csr_src,
    const float* __restrict__ dinv, const f16* __restrict__ h,
    const float* __restrict__ b1, const float* __restrict__ W2,
    float* __restrict__ z, int N) {
  int wave = (blockIdx.x * blockDim.x + threadIdx.x) >> 6;
  int lane = threadIdx.x & 63;
  int half = lane >> 5;
  int l = lane & 31;
  int d = wave * 2 + half;
  bool valid = d < N;
  if (!valid) d = N - 1;
  float dd = dinv[d];
  int beg = rowptr[d], end = rowptr[d + 1];
  int f0 = l << 3;  // 8 features per lane

  float acc[8];
  {
    F16x8 hv;
    hv.q = *(const uint4*)(h + ((size_t)d << 8) + f0);
    float sw = dd * dd;
#pragma unroll
    for (int i = 0; i < 8; ++i) acc[i] = (float)hv.v[i] * sw;
  }

  int e = beg;
  for (; e + 1 < end; e += 2) {
    int s0 = csr_src[e];
    int s1 = csr_src[e + 1];
    F16x8 a, b;
    a.q = *(const uint4*)(h + ((size_t)s0 << 8) + f0);
    b.q = *(const uint4*)(h + ((size_t)s1 << 8) + f0);
    float n0 = dinv[s0] * dd;
    float n1 = dinv[s1] * dd;
#pragma unroll
    for (int i = 0; i < 8; ++i) acc[i] += n0 * (float)a.v[i] + n1 * (float)b.v[i];
  }
  if (e < end) {
    int s0 = csr_src[e];
    F16x8 a;
    a.q = *(const uint4*)(h + ((size_t)s0 << 8) + f0);
    float n0 = dinv[s0] * dd;
#pragma unroll
    for (int i = 0; i < 8; ++i) acc[i] += n0 * (float)a.v[i];
  }

  // epilogue: bias, elu, threefry dropout, dot W2 (8 feats/lane)
  float4 bb0 = *(const float4*)(b1 + f0);
  float4 bb1 = *(const float4*)(b1 + f0 + 4);
  float4 w0  = *(const float4*)(W2 + f0);
  float4 w1  = *(const float4*)(W2 + f0 + 4);
  const float* bbp[8] = {&bb0.x, &bb0.y, &bb0.z, &bb0.w, &bb1.x, &bb1.y, &bb1.z, &bb1.w};
  const float* wp[8]  = {&w0.x, &w0.y, &w0.z, &w0.w, &w1.x, &w1.y, &w1.z, &w1.w};

  float sum = 0.f;
  uint32_t jbase = ((uint32_t)d << 8) + (uint32_t)f0;
#pragma unroll
  for (int i = 0; i < 8; ++i) {
    uint32_t r0, r1;
    threefry_0_42(0u, jbase + i, r0, r1);  // ctr = (hi=0, lo=j)
    uint32_t bits = r0 ^ r1;
    float u = __uint_as_float((bits >> 9) | 0x3f800000u) - 1.0f;
    float va = acc[i] + *bbp[i];
    float ea = va > 0.f ? va : expm1f(va);
    float ha = (u < 0.75f) ? (ea * (1.0f / 0.75f)) : 0.f;
    sum += ha * *wp[i];
  }
#pragma unroll
  for (int off = 16; off > 0; off >>= 1) sum += __shfl_down(sum, off, 32);
  if (l == 0 && valid) z[d] = sum;
}

// ------- gather layer 2 (scalar feature): one wave per node ----------------
__global__ __launch_bounds__(256) void k_gather2(
    const int* __restrict__ rowptr, const int* __restrict__ csr_src,
    const float* __restrict__ dinv, const float* __restrict__ z,
    const float* __restrict__ b2, float* __restrict__ out, int N) {
  int wave = (blockIdx.x * blockDim.x + threadIdx.x) >> 6;
  int lane = threadIdx.x & 63;
  if (wave >= N) return;
  int d = wave;
  float dd = dinv[d];
  int beg = rowptr[d], end = rowptr[d + 1];

  float acc = 0.f;
  for (int e = beg + lane; e < end; e += 64) {
    int s = csr_src[e];
    acc += dinv[s] * z[s];
  }
#pragma unroll
  for (int off = 32; off > 0; off >>= 1) acc += __shfl_down(acc, off, 64);
  if (lane == 0) out[d] = b2[0] + dd * dd * z[d] + dd * acc;
}

// ---------------------------------------------------------------------------
extern "C" void kernel_launch(void* const* d_in, const int* in_sizes, int n_in,
                              void* d_out, int out_size, void* d_ws, size_t ws_size,
                              hipStream_t stream) {
  const float* x  = (const float*)d_in[0];
  const int*   ei = (const int*)d_in[1];   // [2,E] int32
  const float* W1 = (const float*)d_in[2];
  const float* b1 = (const float*)d_in[3];
  const float* W2 = (const float*)d_in[4];
  const float* b2 = (const float*)d_in[5];
  float* out = (float*)d_out;

  const int E = in_sizes[1] / 2;
  const int N = in_sizes[0] / 512;  // 50000
  const int* src = ei;
  const int* dst = ei + E;

  char* ws = (char*)d_ws;
  size_t off = 0;
  auto alloc = [&](size_t bytes) -> void* {
    void* p = ws + off;
    off += (bytes + 255) & ~(size_t)255;
    return p;
  };
  int*   deg     = (int*)  alloc((size_t)N * 4);
  int*   rowptr  = (int*)  alloc((size_t)(N + 1) * 4);
  int*   cursor  = (int*)  alloc((size_t)N * 4);
  int*   csr_src = (int*)  alloc((size_t)E * 4);          // 3.2 MB
  int*   sums    = (int*)  alloc(1024 * 4);
  float* dinv    = (float*)alloc((size_t)N * 4);
  f16*   h       = (f16*)  alloc((size_t)N * 256 * 2);    // 25.6 MB
  float* z       = (float*)alloc((size_t)N * 4);
  uint4* Bpk     = (uint4*)alloc(32768 * 16);             // 512 KB packed W1T

  const int nb = (N + 255) / 256;  // scan blocks

  hipMemsetAsync(deg, 0, (size_t)N * 4, stream);
  k_prep_w1t<<<(512 * 256 + 255) / 256, 256, 0, stream>>>(W1, (unsigned short*)Bpk);
  k_deg<<<(E + 255) / 256, 256, 0, stream>>>(dst, E, deg);
  k_dinv<<<(N + 255) / 256, 256, 0, stream>>>(deg, dinv, N);
  k_scan1<<<nb, 256, 0, stream>>>(deg, rowptr, sums, N);
  k_scan2<<<1, 1024, 0, stream>>>(sums, nb);
  k_scan3<<<(N + 255) / 256, 256, 0, stream>>>(rowptr, sums, N, E);
  hipMemcpyAsync(cursor, rowptr, (size_t)N * 4, hipMemcpyDeviceToDevice, stream);
  k_bucket<<<(E + 255) / 256, 256, 0, stream>>>(src, dst, cursor, csr_src, E);

  k_gemm_mfma<<<(N + 31) / 32, 256, 0, stream>>>(x, Bpk, h, N);

  const int nwaves1 = (N + 1) / 2;  // 2 nodes per wave
  k_gather_fused<<<(nwaves1 * 64 + 255) / 256, 256, 0, stream>>>(rowptr, csr_src, dinv, h,
                                                                 b1, W2, z, N);
  k_gather2<<<(N * 64 + 255) / 256, 256, 0, stream>>>(rowptr, csr_src, dinv, z, b2, out, N);
}

// Round 7
// 400.709 us; speedup vs baseline: 1.6898x; 1.0282x over previous
//
#include <hip/hip_runtime.h>
#include <stdint.h>

// ---------------------------------------------------------------------------
// GCN 2-layer: out = Ahat( dropout(elu( Ahat(x@W1)+b1 )) @ W2 ) + b2
// Ahat = D^-1/2 (A+I) D^-1/2
// dropout = jax threefry2x32 key(42), p=0.25, partitionable path.
// R6->R7: GEMM pipelines B-fragment loads (R6: per-ks L2 stall, MfmaUtil 13%);
// h stored pre-scaled by dinv (kills per-edge dinv[s] load); z stored scaled;
// gather2 packs 4 nodes/wave (avg deg 16; 64-lane waves were idle).
// ---------------------------------------------------------------------------

typedef __bf16 bf16x8 __attribute__((ext_vector_type(8)));
typedef float floatx4 __attribute__((ext_vector_type(4)));
typedef _Float16 f16;
typedef _Float16 f16x8 __attribute__((ext_vector_type(8)));

union BF8 {
  bf16x8 v;
  unsigned short u[8];
  uint4 q;
};

union F16x8 {
  f16x8 v;
  uint4 q;
};

// ---------------- Threefry-2x32, key = (0, 42), 20 rounds ------------------
__device__ __forceinline__ void tf_round(uint32_t& x0, uint32_t& x1, int r) {
  x0 += x1;
  x1 = (x1 << r) | (x1 >> (32 - r));
  x1 ^= x0;
}

__device__ __forceinline__ void threefry_0_42(uint32_t c0, uint32_t c1,
                                              uint32_t& o0, uint32_t& o1) {
  const uint32_t ks0 = 0u;
  const uint32_t ks1 = 42u;
  const uint32_t ks2 = 0x1BD11BDAu ^ 0u ^ 42u;
  uint32_t x0 = c0 + ks0;
  uint32_t x1 = c1 + ks1;
  tf_round(x0, x1, 13); tf_round(x0, x1, 15); tf_round(x0, x1, 26); tf_round(x0, x1, 6);
  x0 += ks1; x1 += ks2 + 1u;
  tf_round(x0, x1, 17); tf_round(x0, x1, 29); tf_round(x0, x1, 16); tf_round(x0, x1, 24);
  x0 += ks2; x1 += ks0 + 2u;
  tf_round(x0, x1, 13); tf_round(x0, x1, 15); tf_round(x0, x1, 26); tf_round(x0, x1, 6);
  x0 += ks0; x1 += ks1 + 3u;
  tf_round(x0, x1, 17); tf_round(x0, x1, 29); tf_round(x0, x1, 16); tf_round(x0, x1, 24);
  x0 += ks1; x1 += ks2 + 4u;
  tf_round(x0, x1, 13); tf_round(x0, x1, 15); tf_round(x0, x1, 26); tf_round(x0, x1, 6);
  x0 += ks2; x1 += ks0 + 5u;
  o0 = x0; o1 = x1;
}

// split fp32 -> bf16 hi (truncate) + bf16 lo (truncate of residual)
__device__ __forceinline__ void split_bf16(float x, unsigned short& hi, unsigned short& lo) {
  uint32_t b = __float_as_uint(x);
  hi = (unsigned short)(b >> 16);
  float hif = __uint_as_float(b & 0xffff0000u);
  float lof = x - hif;  // exact
  lo = (unsigned short)(__float_as_uint(lof) >> 16);
}

// ---------------- degree / dinv --------------------------------------------
__global__ void k_deg(const int* __restrict__ dst, int E, int* __restrict__ deg) {
  int e = blockIdx.x * blockDim.x + threadIdx.x;
  if (e < E) atomicAdd(&deg[dst[e]], 1);
}

__global__ void k_dinv(const int* __restrict__ deg, float* __restrict__ dinv, int N) {
  int n = blockIdx.x * blockDim.x + threadIdx.x;
  if (n < N) {
    float d = (float)(deg[n] + 1);  // +1 self loop
    dinv[n] = 1.0f / sqrtf(d);
  }
}

// ---------------- 3-phase exclusive scan -----------------------------------
__global__ __launch_bounds__(256) void k_scan1(const int* __restrict__ deg,
                                               int* __restrict__ excl,
                                               int* __restrict__ sums, int N) {
  __shared__ int sm[256];
  int tid = threadIdx.x;
  int i = blockIdx.x * 256 + tid;
  int v = (i < N) ? deg[i] : 0;
  sm[tid] = v;
  __syncthreads();
#pragma unroll
  for (int off = 1; off < 256; off <<= 1) {
    int t = (tid >= off) ? sm[tid - off] : 0;
    __syncthreads();
    sm[tid] += t;
    __syncthreads();
  }
  if (i < N) excl[i] = sm[tid] - v;
  if (tid == 255) sums[blockIdx.x] = sm[255];
}

__global__ __launch_bounds__(1024) void k_scan2(int* __restrict__ sums, int nb) {
  __shared__ int sm[1024];
  int tid = threadIdx.x;
  int v = (tid < nb) ? sums[tid] : 0;
  sm[tid] = v;
  __syncthreads();
#pragma unroll
  for (int off = 1; off < 1024; off <<= 1) {
    int t = (tid >= off) ? sm[tid - off] : 0;
    __syncthreads();
    sm[tid] += t;
    __syncthreads();
  }
  if (tid < nb) sums[tid] = sm[tid] - v;  // exclusive, in place
}

__global__ void k_scan3(int* __restrict__ rowptr, const int* __restrict__ sums,
                        int N, int E) {
  int i = blockIdx.x * blockDim.x + threadIdx.x;
  if (i < N) rowptr[i] += sums[i >> 8];
  if (i == 0) rowptr[N] = E;
}

// ---------------- bucket edges by dst --------------------------------------
__global__ void k_bucket(const int* __restrict__ src, const int* __restrict__ dst,
                         int* __restrict__ cursor, int* __restrict__ csr_src, int E) {
  int e = blockIdx.x * blockDim.x + threadIdx.x;
  if (e < E) {
    int pos = atomicAdd(&cursor[dst[e]], 1);
    csr_src[pos] = src[e];
  }
}

// -------- prep: W1 [512][256] fp32 -> packed fragment-major bf16 hi/lo -----
// uint4 entry index = ((ks*16 + nt)*2 + plane)*64 + lane;
// lane = quad*16 + (n&15), k = ks*32 + quad*8 + j, nt = n>>4.
__global__ void k_prep_w1t(const float* __restrict__ W1,
                           unsigned short* __restrict__ Bpk) {
  int t = blockIdx.x * blockDim.x + threadIdx.x;  // t = k*256+n
  if (t >= 512 * 256) return;
  int k = t >> 8, n = t & 255;
  unsigned short hi, lo;
  split_bf16(W1[t], hi, lo);
  int ks = k >> 5, quad = (k >> 3) & 3, j = k & 7;
  int nt = n >> 4, lane = quad * 16 + (n & 15);
  size_t ehi = ((size_t)(ks * 16 + nt) * 2) * 64 + lane;
  Bpk[ehi * 8 + j] = hi;
  Bpk[(ehi + 64) * 8 + j] = lo;
}

// -------- GEMM1: hs = (f16) dinv ⊙ (x @ W1) --------------------------------
// wave-tile: 32 rows x 64 cols; block = 4 waves = 32 rows x 256 cols.
// A and B both software-pipelined (B stall was R6's limiter).
__global__ __launch_bounds__(256) void k_gemm_mfma(
    const float* __restrict__ A,     // [M,512]
    const uint4* __restrict__ Bpk,   // packed, 32768 uint4 (512 KB, L2-hot)
    const float* __restrict__ dinv,  // [M]
    f16* __restrict__ C,             // [M,256] scaled output
    int M) {
  const int K = 512;
  const int cg = threadIdx.x >> 6;     // col group: nt = cg*4 .. cg*4+3
  const int lane = threadIdx.x & 63;
  const int quad = lane >> 4;
  const int l16 = lane & 15;

  const int m0 = blockIdx.x * 32;
  int r0 = m0 + l16;
  int r1 = m0 + 16 + l16;
  const float* a0p = A + (size_t)(r0 < M ? r0 : M - 1) * K;
  const float* a1p = A + (size_t)(r1 < M ? r1 : M - 1) * K;

  floatx4 acc[2][4];
#pragma unroll
  for (int f = 0; f < 2; ++f)
#pragma unroll
    for (int t = 0; t < 4; ++t) acc[f][t] = (floatx4){0.f, 0.f, 0.f, 0.f};

  // prefetched A registers (k-step 0)
  float4 x0 = *(const float4*)(a0p + quad * 8);
  float4 x1 = *(const float4*)(a0p + quad * 8 + 4);
  float4 y0 = *(const float4*)(a1p + quad * 8);
  float4 y1 = *(const float4*)(a1p + quad * 8 + 4);

  // prefetched B registers (k-step 0)
  const uint4* bp0 = Bpk + lane + (size_t)(cg * 4) * 128;
  BF8 bh[4], bl[4];
#pragma unroll
  for (int t = 0; t < 4; ++t) {
    bh[t].q = bp0[t * 128];
    bl[t].q = bp0[t * 128 + 64];
  }

  for (int ks = 0; ks < 16; ++ks) {
    // convert current A to hi/lo bf16
    BF8 ahi0, alo0, ahi1, alo1;
    {
      float xv[8] = {x0.x, x0.y, x0.z, x0.w, x1.x, x1.y, x1.z, x1.w};
      float yv[8] = {y0.x, y0.y, y0.z, y0.w, y1.x, y1.y, y1.z, y1.w};
#pragma unroll
      for (int j = 0; j < 8; ++j) {
        split_bf16(xv[j], ahi0.u[j], alo0.u[j]);
        split_bf16(yv[j], ahi1.u[j], alo1.u[j]);
      }
    }

    // prefetch next k-step's A and B while MFMAs run
    BF8 nbh[4], nbl[4];
    if (ks < 15) {
      const int kb = (ks + 1) * 32 + quad * 8;
      x0 = *(const float4*)(a0p + kb);
      x1 = *(const float4*)(a0p + kb + 4);
      y0 = *(const float4*)(a1p + kb);
      y1 = *(const float4*)(a1p + kb + 4);
      const uint4* np = bp0 + (size_t)(ks + 1) * 2048;
#pragma unroll
      for (int t = 0; t < 4; ++t) {
        nbh[t].q = np[t * 128];
        nbl[t].q = np[t * 128 + 64];
      }
    }

#pragma unroll
    for (int t = 0; t < 4; ++t) {
      acc[0][t] = __builtin_amdgcn_mfma_f32_16x16x32_bf16(ahi0.v, bh[t].v, acc[0][t], 0, 0, 0);
      acc[0][t] = __builtin_amdgcn_mfma_f32_16x16x32_bf16(alo0.v, bh[t].v, acc[0][t], 0, 0, 0);
      acc[0][t] = __builtin_amdgcn_mfma_f32_16x16x32_bf16(ahi0.v, bl[t].v, acc[0][t], 0, 0, 0);
      acc[1][t] = __builtin_amdgcn_mfma_f32_16x16x32_bf16(ahi1.v, bh[t].v, acc[1][t], 0, 0, 0);
      acc[1][t] = __builtin_amdgcn_mfma_f32_16x16x32_bf16(alo1.v, bh[t].v, acc[1][t], 0, 0, 0);
      acc[1][t] = __builtin_amdgcn_mfma_f32_16x16x32_bf16(ahi1.v, bl[t].v, acc[1][t], 0, 0, 0);
    }

#pragma unroll
    for (int t = 0; t < 4; ++t) {
      bh[t] = nbh[t];
      bl[t] = nbl[t];
    }
  }

  // store hs = dinv[row] * acc; C/D layout col=lane&15, row=quad*4+reg
#pragma unroll
  for (int f = 0; f < 2; ++f)
#pragma unroll
    for (int r = 0; r < 4; ++r) {
      int gm = m0 + f * 16 + quad * 4 + r;
      if (gm < M) {
        float dv = dinv[gm];
#pragma unroll
        for (int t = 0; t < 4; ++t) {
          const int col = (cg * 4 + t) * 16 + l16;
          C[(size_t)gm * 256 + col] = (f16)(dv * acc[f][t][r]);
        }
      }
    }
}

// ------- fused gather1 + (+b1 -> elu -> dropout -> dot W2) -----------------
// hs is pre-scaled by dinv. agg[d] = dd*(hs[d] + Σ hs[s]).
// one wave serves TWO nodes (half-wave each); lane covers 8 fp16 feats (16B).
// stores zs[d] = dd * z[d] (pre-scaled for layer-2 gather).
__global__ __launch_bounds__(256) void k_gather_fused(
    const int* __restrict__ rowptr, const int* __restrict__ csr_src,
    const float* __restrict__ dinv, const f16* __restrict__ hs,
    const float* __restrict__ b1, const float* __restrict__ W2,
    float* __restrict__ zs, int N) {
  int wave = (blockIdx.x * blockDim.x + threadIdx.x) >> 6;
  int lane = threadIdx.x & 63;
  int half = lane >> 5;
  int l = lane & 31;
  int d = wave * 2 + half;
  bool valid = d < N;
  if (!valid) d = N - 1;
  float dd = dinv[d];
  int beg = rowptr[d], end = rowptr[d + 1];
  int f0 = l << 3;  // 8 features per lane

  float acc[8];
  {
    F16x8 hv;
    hv.q = *(const uint4*)(hs + ((size_t)d << 8) + f0);
#pragma unroll
    for (int i = 0; i < 8; ++i) acc[i] = (float)hv.v[i];
  }

  int e = beg;
  for (; e + 3 < end; e += 4) {
    int s0 = csr_src[e], s1 = csr_src[e + 1], s2 = csr_src[e + 2], s3 = csr_src[e + 3];
    F16x8 a, b, c, dq;
    a.q = *(const uint4*)(hs + ((size_t)s0 << 8) + f0);
    b.q = *(const uint4*)(hs + ((size_t)s1 << 8) + f0);
    c.q = *(const uint4*)(hs + ((size_t)s2 << 8) + f0);
    dq.q = *(const uint4*)(hs + ((size_t)s3 << 8) + f0);
#pragma unroll
    for (int i = 0; i < 8; ++i)
      acc[i] += (float)a.v[i] + (float)b.v[i] + (float)c.v[i] + (float)dq.v[i];
  }
  for (; e < end; ++e) {
    int s0 = csr_src[e];
    F16x8 a;
    a.q = *(const uint4*)(hs + ((size_t)s0 << 8) + f0);
#pragma unroll
    for (int i = 0; i < 8; ++i) acc[i] += (float)a.v[i];
  }

  // epilogue: scale by dd, bias, elu, threefry dropout, dot W2
  float4 bb0 = *(const float4*)(b1 + f0);
  float4 bb1 = *(const float4*)(b1 + f0 + 4);
  float4 w0  = *(const float4*)(W2 + f0);
  float4 w1  = *(const float4*)(W2 + f0 + 4);
  const float* bbp[8] = {&bb0.x, &bb0.y, &bb0.z, &bb0.w, &bb1.x, &bb1.y, &bb1.z, &bb1.w};
  const float* wp[8]  = {&w0.x, &w0.y, &w0.z, &w0.w, &w1.x, &w1.y, &w1.z, &w1.w};

  float sum = 0.f;
  uint32_t jbase = ((uint32_t)d << 8) + (uint32_t)f0;
#pragma unroll
  for (int i = 0; i < 8; ++i) {
    uint32_t r0, r1;
    threefry_0_42(0u, jbase + i, r0, r1);  // ctr = (hi=0, lo=j)
    uint32_t bits = r0 ^ r1;
    float u = __uint_as_float((bits >> 9) | 0x3f800000u) - 1.0f;
    float va = dd * acc[i] + *bbp[i];
    float ea = va > 0.f ? va : expm1f(va);
    float ha = (u < 0.75f) ? (ea * (1.0f / 0.75f)) : 0.f;
    sum += ha * *wp[i];
  }
#pragma unroll
  for (int off = 16; off > 0; off >>= 1) sum += __shfl_down(sum, off, 32);
  if (l == 0 && valid) zs[d] = dd * sum;
}

// ------- gather layer 2: out[d] = b2 + dd*(zs[d] + Σ zs[s]) ----------------
// 4 nodes per wave (16 lanes each; avg degree ~16)
__global__ __launch_bounds__(256) void k_gather2(
    const int* __restrict__ rowptr, const int* __restrict__ csr_src,
    const float* __restrict__ dinv, const float* __restrict__ zs,
    const float* __restrict__ b2, float* __restrict__ out, int N) {
  int wave = (blockIdx.x * blockDim.x + threadIdx.x) >> 6;
  int lane = threadIdx.x & 63;
  int sub = lane >> 4;   // 0..3
  int l = lane & 15;
  int d = wave * 4 + sub;
  bool valid = d < N;
  if (!valid) d = N - 1;
  float dd = dinv[d];
  int beg = rowptr[d], end = rowptr[d + 1];

  float acc = 0.f;
  for (int e = beg + l; e < end; e += 16) {
    acc += zs[csr_src[e]];
  }
#pragma unroll
  for (int off = 8; off > 0; off >>= 1) acc += __shfl_down(acc, off, 16);
  if (l == 0 && valid) out[d] = b2[0] + dd * (zs[d] + acc);
}

// ---------------------------------------------------------------------------
extern "C" void kernel_launch(void* const* d_in, const int* in_sizes, int n_in,
                              void* d_out, int out_size, void* d_ws, size_t ws_size,
                              hipStream_t stream) {
  const float* x  = (const float*)d_in[0];
  const int*   ei = (const int*)d_in[1];   // [2,E] int32
  const float* W1 = (const float*)d_in[2];
  const float* b1 = (const float*)d_in[3];
  const float* W2 = (const float*)d_in[4];
  const float* b2 = (const float*)d_in[5];
  float* out = (float*)d_out;

  const int E = in_sizes[1] / 2;
  const int N = in_sizes[0] / 512;  // 50000
  const int* src = ei;
  const int* dst = ei + E;

  char* ws = (char*)d_ws;
  size_t off = 0;
  auto alloc = [&](size_t bytes) -> void* {
    void* p = ws + off;
    off += (bytes + 255) & ~(size_t)255;
    return p;
  };
  int*   deg     = (int*)  alloc((size_t)N * 4);
  int*   rowptr  = (int*)  alloc((size_t)(N + 1) * 4);
  int*   cursor  = (int*)  alloc((size_t)N * 4);
  int*   csr_src = (int*)  alloc((size_t)E * 4);          // 3.2 MB
  int*   sums    = (int*)  alloc(1024 * 4);
  float* dinv    = (float*)alloc((size_t)N * 4);
  f16*   hs      = (f16*)  alloc((size_t)N * 256 * 2);    // 25.6 MB
  float* zs      = (float*)alloc((size_t)N * 4);
  uint4* Bpk     = (uint4*)alloc(32768 * 16);             // 512 KB packed W1T

  const int nb = (N + 255) / 256;  // scan blocks

  hipMemsetAsync(deg, 0, (size_t)N * 4, stream);
  k_prep_w1t<<<(512 * 256 + 255) / 256, 256, 0, stream>>>(W1, (unsigned short*)Bpk);
  k_deg<<<(E + 255) / 256, 256, 0, stream>>>(dst, E, deg);
  k_dinv<<<(N + 255) / 256, 256, 0, stream>>>(deg, dinv, N);
  k_scan1<<<nb, 256, 0, stream>>>(deg, rowptr, sums, N);
  k_scan2<<<1, 1024, 0, stream>>>(sums, nb);
  k_scan3<<<(N + 255) / 256, 256, 0, stream>>>(rowptr, sums, N, E);
  hipMemcpyAsync(cursor, rowptr, (size_t)N * 4, hipMemcpyDeviceToDevice, stream);
  k_bucket<<<(E + 255) / 256, 256, 0, stream>>>(src, dst, cursor, csr_src, E);

  k_gemm_mfma<<<(N + 31) / 32, 256, 0, stream>>>(x, Bpk, dinv, hs, N);

  const int nwaves1 = (N + 1) / 2;  // 2 nodes per wave
  k_gather_fused<<<(nwaves1 * 64 + 255) / 256, 256, 0, stream>>>(rowptr, csr_src, dinv, hs,
                                                                 b1, W2, zs, N);
  const int nwaves2 = (N + 3) / 4;  // 4 nodes per wave
  k_gather2<<<(nwaves2 * 64 + 255) / 256, 256, 0, stream>>>(rowptr, csr_src, dinv, zs, b2, out, N);
}